// Round 9
// baseline (294.659 us; speedup 1.0000x reference)
//
#include <hip/hip_runtime.h>
#include <math.h>

// NoisyTopKRouter, round 9: barrier-free K-quarter split @ 4 waves/SIMD + in-run ablation.
//   router_mfma<0>: 512 thr = 8 waves (4 kq x 2 nh), BM=32, grid 512, no main-loop barriers,
//                   B JIT from L2/L3, A reg-dbuf, setprio; 4-phase LDS reduce + epilogue.
//   router_mfma<1>: identical, but B reads pinned (opaque) to an L2-hot window, no output.
//                   Diagnostic: T_diag = dur_total - T_primary - pack isolates B-fetch cost.
// Outputs (flat f32): gate_weights [N][64], top2 idx as float [N][2], logits [N][64].

typedef float   f32x4   __attribute__((ext_vector_type(4)));
typedef __bf16  bf16x8  __attribute__((ext_vector_type(8)));
typedef unsigned short ushort8 __attribute__((ext_vector_type(8)));

#define EE 64     // experts
#define E2 128    // gate+noise logit columns
#define BM 32     // tokens per block

__device__ __forceinline__ unsigned short bf16_rne(float f) {
    unsigned int u = __float_as_uint(f);
    u += 0x7fffu + ((u >> 16) & 1u);
    return (unsigned short)(u >> 16);
}
__device__ __forceinline__ float bf16_f32(unsigned short h) {
    return __uint_as_float(((unsigned int)h) << 16);
}
__device__ __forceinline__ void split3(float a, unsigned short& h1,
                                       unsigned short& h2, unsigned short& h3) {
    h1 = bf16_rne(a);
    float r  = a - bf16_f32(h1);     // exact
    h2 = bf16_rne(r);
    float r2 = r - bf16_f32(h2);     // exact
    h3 = bf16_rne(r2);
}

// ---- pre-kernel: pack W (gate cols 0..63, noise cols 64..127) into B-frag order.
// Fragment (16x16x32 bf16, verified): lane l holds col=l&15, k=(l>>4)*8+j.
// Packed ushort addr: ((ks*8 + nt)*3 + term)*512 + lane*8 + j   (ks = k/32)
__global__ __launch_bounds__(256) void pack_b(
    const float* __restrict__ wg, const float* __restrict__ wn,
    unsigned short* __restrict__ bp, int Hdim)
{
    int pair = blockIdx.x * 4 + (threadIdx.x >> 6);   // (ks, nt)
    int l    = threadIdx.x & 63;
    int ks   = pair >> 3;
    int nt   = pair & 7;
    int col  = nt * 16 + (l & 15);
    int k    = ks * 32 + ((l >> 4) * 8);
    const float* wrow = (col < EE) ? (wg + (size_t)col * Hdim)
                                   : (wn + (size_t)(col - EE) * Hdim);
    float4 v0 = *reinterpret_cast<const float4*>(wrow + k);
    float4 v1 = *reinterpret_cast<const float4*>(wrow + k + 4);
    float vals[8] = {v0.x, v0.y, v0.z, v0.w, v1.x, v1.y, v1.z, v1.w};
    ushort8 t1, t2, t3;
    #pragma unroll
    for (int j = 0; j < 8; ++j) {
        unsigned short a, b, c;
        split3(vals[j], a, b, c);
        t1[j] = a; t2[j] = b; t3[j] = c;
    }
    size_t base = ((size_t)(ks * 8 + nt) * 3) * 512 + (size_t)l * 8;
    *reinterpret_cast<ushort8*>(bp + base        ) = t1;
    *reinterpret_cast<ushort8*>(bp + base + 512  ) = t2;
    *reinterpret_cast<ushort8*>(bp + base + 1024 ) = t3;
}

#define MFMA(a, b, c) __builtin_amdgcn_mfma_f32_16x16x32_bf16((a), (b), (c), 0, 0, 0)

template<int DIAG>
__global__ __launch_bounds__(512, 4) void router_mfma(
    const float* __restrict__ hs,
    const float* __restrict__ noise,
    const unsigned short* __restrict__ bp,
    float* __restrict__ out_gate,
    float* __restrict__ out_idx,
    float* __restrict__ out_logits,
    int Ntok, int Hdim)
{
    __shared__ float Lred[BM][E2 + 5];   // stride 133 -> conflict-free scalar reads

    const int tid  = threadIdx.x;
    const int lane = tid & 63;
    const int w    = tid >> 6;           // wave 0..7
    const int kq   = w & 3;              // K-quarter 0..3
    const int nh   = w >> 2;             // N-half 0..1 (cols nh*64 .. nh*64+63)
    const int m0   = blockIdx.x * BM;

    const int kquart = Hdim >> 2;        // 1024
    const int steps  = kquart >> 5;      // 32 (even)

    unsigned opq = 0;
    if (DIAG) asm volatile("s_mov_b32 %0, 0" : "=s"(opq));  // opaque zero

    f32x4 acc[2][4];
    #pragma unroll
    for (int mt = 0; mt < 2; ++mt)
        #pragma unroll
        for (int n = 0; n < 4; ++n) acc[mt][n] = f32x4{0.f, 0.f, 0.f, 0.f};

    // A sources: lane l covers row (l&15) of m-tile, k-octet (l>>4)*8, this wave's quarter.
    const float* pa0 = hs + (size_t)(m0 + (lane & 15)) * Hdim
                          + (size_t)kq * kquart + ((lane >> 4) * 8);
    const float* pa1 = pa0 + (size_t)16 * Hdim;

    // B base for this wave: nh selects nt-tiles [nh*4, nh*4+4).
    const unsigned short* pbw = bp + (size_t)(nh * 12) * 512 + (size_t)lane * 8;
    const int ks0 = kq * steps;

    #define LOADA(d00, d01, d10, d11)                                         \
        do {                                                                  \
            d00 = *reinterpret_cast<const float4*>(pa0);                      \
            d01 = *reinterpret_cast<const float4*>(pa0 + 4);                  \
            d10 = *reinterpret_cast<const float4*>(pa1);                      \
            d11 = *reinterpret_cast<const float4*>(pa1 + 4);                  \
            pa0 += 32; pa1 += 32;                                             \
        } while (0)

    #define SPLIT(s0, s1, A1, A2, A3)                                         \
        do {                                                                  \
            float vals[8] = {s0.x, s0.y, s0.z, s0.w, s1.x, s1.y, s1.z, s1.w}; \
            _Pragma("unroll")                                                 \
            for (int j = 0; j < 8; ++j) {                                     \
                float a  = vals[j];                                           \
                __bf16 h1 = (__bf16)a;                                        \
                float r  = a - (float)h1;                                     \
                __bf16 h2 = (__bf16)r;                                        \
                float r2 = r - (float)h2;                                     \
                __bf16 h3 = (__bf16)r2;                                       \
                A1[j] = h1; A2[j] = h2; A3[j] = h3;                           \
            }                                                                 \
        } while (0)

    #define COMPUTE(s, a00, a01, a10, a11)                                    \
        do {                                                                  \
            int ks = ks0 + (s);                                               \
            if (DIAG) ks = (ks & (int)opq) + ks0;   /* pin to L2-hot window */ \
            const unsigned short* pb = pbw + (size_t)ks * 12288;              \
            bf16x8 A1a, A2a, A3a, A1b, A2b, A3b;                              \
            SPLIT(a00, a01, A1a, A2a, A3a);                                   \
            SPLIT(a10, a11, A1b, A2b, A3b);                                   \
            _Pragma("unroll")                                                 \
            for (int n = 0; n < 4; ++n) {                                     \
                bf16x8 b1 = __builtin_bit_cast(bf16x8, *reinterpret_cast<const ushort8*>(pb + (n * 3 + 0) * 512)); \
                bf16x8 b2 = __builtin_bit_cast(bf16x8, *reinterpret_cast<const ushort8*>(pb + (n * 3 + 1) * 512)); \
                bf16x8 b3 = __builtin_bit_cast(bf16x8, *reinterpret_cast<const ushort8*>(pb + (n * 3 + 2) * 512)); \
                __builtin_amdgcn_s_setprio(1);                                \
                acc[0][n] = MFMA(A1a, b1, acc[0][n]);                         \
                acc[0][n] = MFMA(A1a, b2, acc[0][n]);                         \
                acc[0][n] = MFMA(A2a, b1, acc[0][n]);                         \
                acc[0][n] = MFMA(A2a, b2, acc[0][n]);                         \
                acc[0][n] = MFMA(A1a, b3, acc[0][n]);                         \
                acc[0][n] = MFMA(A3a, b1, acc[0][n]);                         \
                acc[1][n] = MFMA(A1b, b1, acc[1][n]);                         \
                acc[1][n] = MFMA(A1b, b2, acc[1][n]);                         \
                acc[1][n] = MFMA(A2b, b1, acc[1][n]);                         \
                acc[1][n] = MFMA(A2b, b2, acc[1][n]);                         \
                acc[1][n] = MFMA(A1b, b3, acc[1][n]);                         \
                acc[1][n] = MFMA(A3b, b1, acc[1][n]);                         \
                __builtin_amdgcn_s_setprio(0);                                \
            }                                                                 \
        } while (0)

    // ---- software-pipelined, barrier-free main loop (parity-named reg sets) ----
    float4 c00, c01, c10, c11, n00, n01, n10, n11;
    LOADA(c00, c01, c10, c11);
    for (int s = 0; s < steps; s += 2) {
        LOADA(n00, n01, n10, n11);                       // prefetch s+1
        COMPUTE(s, c00, c01, c10, c11);
        if (s + 2 < steps) LOADA(c00, c01, c10, c11);    // prefetch s+2
        COMPUTE(s + 1, n00, n01, n10, n11);
    }

    if (!DIAG) {
        // ---- 4-phase cross-quarter reduction (nh-waves write disjoint cols) ----
        // C/D frag (verified): reg r -> row=(lane>>4)*4+r, col=lane&15.
        #pragma unroll
        for (int p = 0; p < 4; ++p) {
            if (kq == p) {
                #pragma unroll
                for (int mt = 0; mt < 2; ++mt)
                    #pragma unroll
                    for (int n = 0; n < 4; ++n)
                        #pragma unroll
                        for (int r = 0; r < 4; ++r) {
                            int row = mt * 16 + (lane >> 4) * 4 + r;
                            int col = (nh * 4 + n) * 16 + (lane & 15);
                            if (p == 0) Lred[row][col]  = acc[mt][n][r];
                            else        Lred[row][col] += acc[mt][n][r];
                        }
            }
            __syncthreads();
        }

        // ---- per-token epilogue (proven path): one thread per token ----
        if (tid < BM) {
            const int t   = tid;
            const int tok = m0 + t;
            const float* nrow = noise + (size_t)tok * EE;
            float* lrow = out_logits + (size_t)tok * EE;

            float m = -3.4e38f;
            for (int e = 0; e < EE; ++e) {
                float gv = Lred[t][e];
                float nv = Lred[t][EE + e];
                float sp = fmaxf(nv, 0.f) + log1pf(expf(-fabsf(nv)));  // stable softplus
                float l  = fmaf(nrow[e], sp, gv);                      // NOISE_STD = 1
                lrow[e]  = l;
                Lred[t][e] = l;
                m = fmaxf(m, l);
            }

            float Z = 0.f;
            float p1 = -1.f, p2 = -1.f;
            int   i1 = 0,    i2 = 0;
            for (int e = 0; e < EE; ++e) {
                float p = expf(Lred[t][e] - m);
                Z += p;
                if (p > p1)      { p2 = p1; i2 = i1; p1 = p; i1 = e; }  // ties -> lower idx
                else if (p > p2) { p2 = p;  i2 = e; }
            }
            float q1 = p1 / Z, q2 = p2 / Z;
            float denom = q1 + q2 + 1e-9f;
            float w1 = q1 / denom, w2 = q2 / denom;

            out_idx[(size_t)tok * 2 + 0] = (float)i1;
            out_idx[(size_t)tok * 2 + 1] = (float)i2;

            float* grow = out_gate + (size_t)tok * EE;
            for (int e = 0; e < EE; ++e)
                grow[e] = (e == i1) ? w1 : ((e == i2) ? w2 : 0.f);
        }
    } else {
        // keepalive: opaque-false guard keeps accs (and thus MFMAs + loads) live,
        // never writes (rule 17: ablation without DCE).
        float ssum = 0.f;
        #pragma unroll
        for (int mt = 0; mt < 2; ++mt)
            #pragma unroll
            for (int n = 0; n < 4; ++n)
                #pragma unroll
                for (int r = 0; r < 4; ++r) ssum += acc[mt][n][r];
        unsigned keep;
        asm volatile("s_mov_b32 %0, 0" : "=s"(keep));
        if (keep) out_logits[(size_t)m0 * EE + tid] = ssum;
    }
}

extern "C" void kernel_launch(void* const* d_in, const int* in_sizes, int n_in,
                              void* d_out, int out_size, void* d_ws, size_t ws_size,
                              hipStream_t stream) {
    const float* hs    = (const float*)d_in[0];
    const float* noise = (const float*)d_in[1];
    const float* wg    = (const float*)d_in[2];
    const float* wn    = (const float*)d_in[3];

    const int Ntok = in_sizes[1] / EE;    // noise is [N][64]
    const int Hdim = in_sizes[2] / EE;    // w_gate is [64][H]

    float* out_gate   = (float*)d_out;
    float* out_idx    = out_gate + (size_t)Ntok * EE;
    float* out_logits = out_idx  + (size_t)Ntok * 2;

    unsigned short* bp = (unsigned short*)d_ws;   // needs (H/32)*8*3*512*2 = 3 MB

    // pack W into MFMA B-fragment layout (3 bf16 terms)
    int pairs = (Hdim / 32) * 8;
    hipLaunchKernelGGL(pack_b, dim3(pairs / 4), dim3(256), 0, stream, wg, wn, bp, Hdim);

    // primary (correct output)
    hipLaunchKernelGGL((router_mfma<0>), dim3(Ntok / BM), dim3(512), 0, stream,
                       hs, noise, bp, out_gate, out_idx, out_logits, Ntok, Hdim);
    // diagnostic (B pinned L2-hot, no output) — time isolated via dur_total subtraction
    hipLaunchKernelGGL((router_mfma<1>), dim3(Ntok / BM), dim3(512), 0, stream,
                       hs, noise, bp, out_gate, out_idx, out_logits, Ntok, Hdim);
}